// Round 2
// baseline (271.779 us; speedup 1.0000x reference)
//
#include <hip/hip_runtime.h>
#include <math.h>

// Hyena filter: k = MLP(z)·decay ; out = irfft(rfft(x,8192)*rfft(k,8192))[:4096] + x*bias
// FFT: rfft(8192 real) via complex FFT of N=4096 (even/odd packing),
// radix-8 Stockham (4 passes), in-place in LDS.
// R5: filter_fft fused into conv. One block per channel d; the filter spectrum
//     is computed once into REGISTERS (thread t owns pair (k=t+512i, 4096-k) in
//     both the filter build and the per-row combine), then the 4 batch rows are
//     processed in a loop. Kills the 67 MB Kf round-trip and one dispatch.
//     All LDS addressing reduced to one VGPR base + immediate offsets via exact
//     identities: PAD(j+512r)=PAD(j)+544r ; PAD(base+8r)=PAD(base)+8r+(r>>1) ;
//     PAD(base+64r)=PAD(base)+68r ; PAD(8j+r)=PAD(8j)+r.   (PAD(i)=i+(i>>4))
//     Next x row prefetched during the current row's forward FFT.

#define PAD(i) ((i) + ((i) >> 4))
#define TWO_PI 6.2831853071795864769f

typedef float2 cplx;

__device__ __forceinline__ cplx cmul(cplx a, cplx b) {
    return make_float2(a.x * b.x - a.y * b.y, a.x * b.y + a.y * b.x);
}

// 8-point DFT, natural order in/out. sgn = -1 forward, +1 inverse (no scaling).
__device__ __forceinline__ void dft8(cplx v[8], float sgn) {
    cplx t;
    t = v[1]; v[1] = v[4]; v[4] = t;   // bit-reversal
    t = v[3]; v[3] = v[6]; v[6] = t;
#pragma unroll
    for (int i = 0; i < 8; i += 2) {
        cplx a = v[i], b = v[i + 1];
        v[i]     = make_float2(a.x + b.x, a.y + b.y);
        v[i + 1] = make_float2(a.x - b.x, a.y - b.y);
    }
#pragma unroll
    for (int i = 0; i < 8; i += 4) {
        cplx a = v[i], b = v[i + 2];
        v[i]     = make_float2(a.x + b.x, a.y + b.y);
        v[i + 2] = make_float2(a.x - b.x, a.y - b.y);
        cplx c1 = v[i + 1], d = v[i + 3];
        cplx dt = make_float2(-sgn * d.y, sgn * d.x);     // * (±i)
        v[i + 1] = make_float2(c1.x + dt.x, c1.y + dt.y);
        v[i + 3] = make_float2(c1.x - dt.x, c1.y - dt.y);
    }
    const float C = 0.70710678118654752440f;
    cplx a, b, bt;
    a = v[0]; b = v[4];
    v[0] = make_float2(a.x + b.x, a.y + b.y);
    v[4] = make_float2(a.x - b.x, a.y - b.y);
    a = v[1]; b = v[5]; bt = cmul(b, make_float2(C, sgn * C));
    v[1] = make_float2(a.x + bt.x, a.y + bt.y);
    v[5] = make_float2(a.x - bt.x, a.y - bt.y);
    a = v[2]; b = v[6]; bt = make_float2(-sgn * b.y, sgn * b.x);
    v[2] = make_float2(a.x + bt.x, a.y + bt.y);
    v[6] = make_float2(a.x - bt.x, a.y - bt.y);
    a = v[3]; b = v[7]; bt = cmul(b, make_float2(-C, sgn * C));
    v[3] = make_float2(a.x + bt.x, a.y + bt.y);
    v[7] = make_float2(a.x - bt.x, a.y - bt.y);
}

// Build w^1..w^7 from one sincos via shallow (depth<=3) cmul chains.
__device__ __forceinline__ void twiddle_powers(float ang, cplx w[8]) {
    float s, c;
    __sincosf(ang, &s, &c);
    w[1] = make_float2(c, s);
    w[2] = cmul(w[1], w[1]);
    w[3] = cmul(w[2], w[1]);
    w[4] = cmul(w[2], w[2]);
    w[5] = cmul(w[4], w[1]);
    w[6] = cmul(w[3], w[3]);
    w[7] = cmul(w[4], w[3]);
}

// One Stockham radix-8 pass over N=4096 in LDS, in place. 512 threads, j = tid.
// Reads at PAD(j)+544r; writes at PAD(base)+{r | 8r+(r>>1) | 68r | 544r}.
template <int NS>
__device__ __forceinline__ void fft_pass_ip(cplx* __restrict__ buf, int j, float sgn) {
    cplx* rp = buf + (j + (j >> 4));
    cplx v[8];
#pragma unroll
    for (int r = 0; r < 8; r++) v[r] = rp[544 * r];
    if (NS > 1) {
        int jm = j & (NS - 1);
        float ang = sgn * (TWO_PI / (float)(NS * 8)) * (float)jm;
        cplx w[8];
        twiddle_powers(ang, w);
#pragma unroll
        for (int r = 1; r < 8; r++) v[r] = cmul(v[r], w[r]);
    }
    dft8(v, sgn);
    __syncthreads();                       // everyone done reading
    int base = ((j & ~(NS - 1)) << 3) + (j & (NS - 1));
    cplx* wp = buf + (base + (base >> 4));
#pragma unroll
    for (int r = 0; r < 8; r++) {
        const int off = (NS == 1) ? r
                      : (NS == 8) ? (8 * r + (r >> 1))
                      : (NS == 64) ? (68 * r)
                      : (544 * r);
        wp[off] = v[r];
    }
    __syncthreads();
}

// Forward FFT pass 1 (NS=1) from registers (xv = lower half, upper half zero).
__device__ __forceinline__ void fft_pass1_fwd_regs(cplx* __restrict__ buf, int j,
                                                   const cplx xv[4]) {
    cplx v[8];
#pragma unroll
    for (int r = 0; r < 4; r++) v[r] = xv[r];
#pragma unroll
    for (int r = 4; r < 8; r++) v[r] = make_float2(0.f, 0.f);
    dft8(v, -1.0f);
    int b8 = 8 * j;
    cplx* wp = buf + (b8 + (b8 >> 4));
#pragma unroll
    for (int r = 0; r < 8; r++) wp[r] = v[r];
    __syncthreads();
}

// ---------------- Kernel 1: positional MLP -> h3T (64 x 4096) ----------------
__global__ __launch_bounds__(256) void mlp_kernel(
    const float* __restrict__ zin, const float* __restrict__ W1,
    const float* __restrict__ b1, const float* __restrict__ freq,
    const float* __restrict__ W2, const float* __restrict__ b2,
    const float* __restrict__ W3, const float* __restrict__ b3,
    float* __restrict__ h3T) {
    __shared__ float hs1[64][64];
    __shared__ float hs2[64][64];
    int tid = threadIdx.x;
    int l = tid & 63, w = tid >> 6;
    int lg = blockIdx.x * 64 + l;          // grid = 64 blocks covers 4096

    float zf[5];
#pragma unroll
    for (int e = 0; e < 5; e++) zf[e] = zin[lg * 5 + e];

    // layer 1
#pragma unroll
    for (int i = 0; i < 16; i++) {
        int o = w * 16 + i;
        float a = b1[o];
#pragma unroll
        for (int e = 0; e < 5; e++) a += W1[o * 5 + e] * zf[e];
        hs1[o][l] = __sinf(freq[o] * a);
    }
    __syncthreads();

    // layer 2
    float acc[16];
#pragma unroll
    for (int i = 0; i < 16; i++) acc[i] = b2[w * 16 + i];
#pragma unroll 8
    for (int o = 0; o < 64; o++) {
        float hv = hs1[o][l];
#pragma unroll
        for (int i = 0; i < 16; i++) acc[i] += W2[(w * 16 + i) * 64 + o] * hv;
    }
#pragma unroll
    for (int i = 0; i < 16; i++)
        hs2[w * 16 + i][l] = __sinf(freq[w * 16 + i] * acc[i]);
    __syncthreads();

    // layer 3
#pragma unroll
    for (int i = 0; i < 16; i++) acc[i] = b3[w * 16 + i];
#pragma unroll 8
    for (int o = 0; o < 64; o++) {
        float hv = hs2[o][l];
#pragma unroll
        for (int i = 0; i < 16; i++) acc[i] += W3[(w * 16 + i) * 64 + o] * hv;
    }
#pragma unroll
    for (int i = 0; i < 16; i++)
        h3T[(size_t)(w * 16 + i) * 4096 + lg] = __sinf(freq[w * 16 + i] * acc[i]);
}

// -------- Kernel 2: k[d,l] = <h3[:,l], W4[d,:]> * exp(-t[l]*|delta[d]|) --------
__global__ __launch_bounds__(256) void kgemm_kernel(
    const float* __restrict__ h3T, const float* __restrict__ W4,
    const float* __restrict__ tvec, const float* __restrict__ deltas,
    float* __restrict__ kout) {
    int lt = blockIdx.x & 3;       // l tile (4 x 1024)
    int dt = blockIdx.x >> 2;      // d tile (64 x 16)
    int l0 = lt * 1024 + threadIdx.x * 4;
    float4 acc[16];
#pragma unroll
    for (int i = 0; i < 16; i++) acc[i] = make_float4(0.f, 0.f, 0.f, 0.f);
#pragma unroll 8
    for (int o = 0; o < 64; o++) {
        float4 h = *(const float4*)(h3T + (size_t)o * 4096 + l0);
#pragma unroll
        for (int i = 0; i < 16; i++) {
            float wv = W4[(size_t)(dt * 16 + i) * 64 + o];
            acc[i].x += wv * h.x; acc[i].y += wv * h.y;
            acc[i].z += wv * h.z; acc[i].w += wv * h.w;
        }
    }
    float4 tl = *(const float4*)(tvec + l0);
#pragma unroll
    for (int i = 0; i < 16; i++) {
        int d = dt * 16 + i;
        float da = fabsf(deltas[d]);
        float4 o;
        o.x = acc[i].x * __expf(-tl.x * da);
        o.y = acc[i].y * __expf(-tl.y * da);
        o.z = acc[i].z * __expf(-tl.z * da);
        o.w = acc[i].w * __expf(-tl.w * da);
        *(float4*)(kout + (size_t)d * 4096 + l0) = o;
    }
}

// ------- Kernel 3 (fused): per channel d: rfft(k) -> regs; then for each of
//         4 batch rows: FFT -> spectral multiply -> IFFT -> +x*bias -> store.
__global__ __launch_bounds__(512) void convf_kernel(
    const float* __restrict__ x, const float* __restrict__ kin,
    const float* __restrict__ bias, float* __restrict__ out) {
    __shared__ cplx buf[4352];
    int d = blockIdx.x;
    int t = threadIdx.x;

    // combine twiddles wk[i] = W8192^(t+512i) = W8192^t * W16^i
    float sb, cb;
    __sincosf(-TWO_PI * (float)t * (1.0f / 8192.0f), &sb, &cb);
    cplx wk[4];
    wk[0] = make_float2(cb, sb);
    wk[1] = cmul(wk[0], make_float2(0.92387953251128675613f, -0.38268343236508977173f));
    wk[2] = cmul(wk[0], make_float2(0.70710678118654752440f, -0.70710678118654752440f));
    wk[3] = cmul(wk[0], make_float2(0.38268343236508977173f, -0.92387953251128675613f));

    // combine/epilogue base pointers: rb -> PAD(t)+544i ; qb2 -> PAD(4096-t)-1632+544(3-i)
    cplx* rb  = buf + (t + (t >> 4));
    cplx* qb2 = buf + (((4096 - t) + ((4096 - t) >> 4)) - 1632);

    // ---- filter: rfft(k row d, 8192) kept in registers ----
    {
        const cplx* k2 = (const cplx*)(kin + (size_t)d * 4096);
        cplx kv[4];
#pragma unroll
        for (int r = 0; r < 4; r++) kv[r] = k2[t + (r << 9)];
        fft_pass1_fwd_regs(buf, t, kv);
        fft_pass_ip<8>(buf, t, -1.0f);
        fft_pass_ip<64>(buf, t, -1.0f);
        fft_pass_ip<512>(buf, t, -1.0f);
    }
    const float scale = 1.0f / 4096.0f;
    cplx Kk[4], Kq[4], Km = make_float2(0.f, 0.f);
#pragma unroll
    for (int i = 0; i < 4; i++) {
        if (t == 0 && i == 0) {            // bins 0, 4096, 2048 (thread 0 only)
            cplx z0 = buf[0];              // PAD(0)=0
            Kk[0] = make_float2((z0.x + z0.y) * scale, (z0.x - z0.y) * scale);
            cplx zm = buf[PAD(2048)];
            Km = make_float2(zm.x * scale, -zm.y * scale);
            Kq[0] = make_float2(0.f, 0.f);
        } else {
            cplx Zk = rb[544 * i];
            cplx Zq = qb2[544 * (3 - i)];
            cplx Fe = make_float2(0.5f * (Zk.x + Zq.x), 0.5f * (Zk.y - Zq.y));
            cplx Fo = make_float2(0.5f * (Zk.y + Zq.y), -0.5f * (Zk.x - Zq.x));
            cplx WFo = cmul(wk[i], Fo);
            Kk[i] = make_float2((Fe.x + WFo.x) * scale, (Fe.y + WFo.y) * scale);
            Kq[i] = make_float2((Fe.x - WFo.x) * scale, -(Fe.y - WFo.y) * scale);
        }
    }

    float bd = bias[d];
    cplx xv[4], xn[4];
    {
        const cplx* xr = (const cplx*)(x + (size_t)d * 4096);   // b = 0 row
#pragma unroll
        for (int r = 0; r < 4; r++) xv[r] = xr[t + (r << 9)];
    }

#pragma unroll 1
    for (int b = 0; b < 4; b++) {
        __syncthreads();                   // previous readers of buf are done
        fft_pass1_fwd_regs(buf, t, xv);
        if (b < 3) {                       // prefetch next row under the FFT
            const cplx* xr = (const cplx*)(x + ((size_t)(b + 1) * 1024 + d) * 4096);
#pragma unroll
            for (int r = 0; r < 4; r++) xn[r] = xr[t + (r << 9)];
        }
        fft_pass_ip<8>(buf, t, -1.0f);
        fft_pass_ip<64>(buf, t, -1.0f);
        fft_pass_ip<512>(buf, t, -1.0f);

        // spectral combine against register-resident filter spectrum
#pragma unroll
        for (int i = 0; i < 4; i++) {
            if (t == 0 && i == 0) {
                cplx z0 = buf[0];
                float U0 = z0.x + z0.y;
                float UN = z0.x - z0.y;
                float Y0 = U0 * Kk[0].x;
                float YN = UN * Kk[0].y;
                buf[0] = make_float2(0.5f * (Y0 + YN), 0.5f * (Y0 - YN));
                cplx zm = buf[PAD(2048)];
                cplx Um = make_float2(zm.x, -zm.y);
                cplx Ym = cmul(Um, Km);
                buf[PAD(2048)] = make_float2(Ym.x, -Ym.y);
            } else {
                cplx Zk = rb[544 * i];
                cplx Zq = qb2[544 * (3 - i)];
                cplx Fe = make_float2(0.5f * (Zk.x + Zq.x), 0.5f * (Zk.y - Zq.y));
                cplx Fo = make_float2(0.5f * (Zk.y + Zq.y), -0.5f * (Zk.x - Zq.x));
                cplx WFo = cmul(wk[i], Fo);
                cplx U1 = make_float2(Fe.x + WFo.x, Fe.y + WFo.y);
                cplx U2 = make_float2(Fe.x - WFo.x, -(Fe.y - WFo.y));
                cplx Y1 = cmul(U1, Kk[i]);
                cplx Y2 = cmul(U2, Kq[i]);
                cplx FeY = make_float2(0.5f * (Y1.x + Y2.x), 0.5f * (Y1.y - Y2.y));
                cplx T   = make_float2(0.5f * (Y1.x - Y2.x), 0.5f * (Y1.y + Y2.y));
                cplx FoY = cmul(make_float2(wk[i].x, -wk[i].y), T);
                rb[544 * i]        = make_float2(FeY.x - FoY.y, FeY.y + FoY.x);
                qb2[544 * (3 - i)] = make_float2(FeY.x + FoY.y, FoY.x - FeY.y);
            }
        }
        __syncthreads();

        // inverse FFT; last pass fused with the global store (only m<2048 needed)
        fft_pass_ip<1>(buf, t, 1.0f);
        fft_pass_ip<8>(buf, t, 1.0f);
        fft_pass_ip<64>(buf, t, 1.0f);
        {
            cplx v[8];
#pragma unroll
            for (int r = 0; r < 8; r++) v[r] = rb[544 * r];
            float ang = (TWO_PI / 4096.0f) * (float)t;   // sgn=+1, NS=512
            cplx w[8];
            twiddle_powers(ang, w);
#pragma unroll
            for (int r = 1; r < 8; r++) v[r] = cmul(v[r], w[r]);
            dft8(v, 1.0f);
            cplx* o2 = (cplx*)(out + ((size_t)b * 1024 + d) * 4096);
#pragma unroll
            for (int r = 0; r < 4; r++) {                // m = t + r*512 < 2048
                cplx o;
                o.x = v[r].x + xv[r].x * bd;
                o.y = v[r].y + xv[r].y * bd;
                o2[t + (r << 9)] = o;
            }
        }
#pragma unroll
        for (int r = 0; r < 4; r++) xv[r] = xn[r];
    }
}

extern "C" void kernel_launch(void* const* d_in, const int* in_sizes, int n_in,
                              void* d_out, int out_size, void* d_ws, size_t ws_size,
                              hipStream_t stream) {
    const float* x      = (const float*)d_in[0];
    // d_in[1] = L (int scalar) — compile-time constant 4096 here
    const float* zin    = (const float*)d_in[2];
    const float* tvec   = (const float*)d_in[3];
    const float* deltas = (const float*)d_in[4];
    const float* W1     = (const float*)d_in[5];
    const float* b1     = (const float*)d_in[6];
    const float* freq   = (const float*)d_in[7];
    const float* W2     = (const float*)d_in[8];
    const float* b2     = (const float*)d_in[9];
    const float* W3     = (const float*)d_in[10];
    const float* b3     = (const float*)d_in[11];
    const float* W4     = (const float*)d_in[12];
    const float* bias   = (const float*)d_in[13];
    float* out = (float*)d_out;

    // ws layout: h3T (64 x 4096 f32 = 1 MB) | kbuf (1024 x 4096 f32 = 16 MB)
    float* h3T  = (float*)d_ws;
    float* kbuf = (float*)((char*)d_ws + (size_t)64 * 4096 * sizeof(float));

    mlp_kernel<<<64, 256, 0, stream>>>(zin, W1, b1, freq, W2, b2, W3, b3, h3T);
    kgemm_kernel<<<256, 256, 0, stream>>>(h3T, W4, tvec, deltas, kbuf);
    convf_kernel<<<1024, 512, 0, stream>>>(x, kbuf, bias, out);
}

// Round 3
// 229.844 us; speedup vs baseline: 1.1825x; 1.1825x over previous
//
#include <hip/hip_runtime.h>
#include <math.h>

// Hyena filter: k = MLP(z)·decay ; out = irfft(rfft(x,8192)*rfft(k,8192))[:4096] + x*bias
// FFT: rfft(8192 real) via complex FFT of N=4096 (even/odd packing),
// radix-8 Stockham (4 passes), in-place in LDS.
// R6: back to the 4-kernel split (R5's register-resident filter fusion pushed
//     VGPR 44->128, halved occupancy, and lost 27us net). Kept from R5: all LDS
//     addressing reduced to one VGPR base + immediate ds offsets via exact
//     identities: PAD(j+512r)=PAD(j)+544r ; PAD(base+8r)=PAD(base)+8r+(r>>1) ;
//     PAD(base+64r)=PAD(base)+68r ; PAD(8j+r)=PAD(8j)+r.   (PAD(i)=i+(i>>4))
//     Twiddles: 1 sincos + shallow cmul power chain per pass; combine twiddle
//     W8192^(t+512i) = W8192^t * W16^i with compile-time W16^i.

#define PAD(i) ((i) + ((i) >> 4))
#define TWO_PI 6.2831853071795864769f

typedef float2 cplx;

__device__ __forceinline__ cplx cmul(cplx a, cplx b) {
    return make_float2(a.x * b.x - a.y * b.y, a.x * b.y + a.y * b.x);
}

// 8-point DFT, natural order in/out. sgn = -1 forward, +1 inverse (no scaling).
__device__ __forceinline__ void dft8(cplx v[8], float sgn) {
    cplx t;
    t = v[1]; v[1] = v[4]; v[4] = t;   // bit-reversal
    t = v[3]; v[3] = v[6]; v[6] = t;
#pragma unroll
    for (int i = 0; i < 8; i += 2) {
        cplx a = v[i], b = v[i + 1];
        v[i]     = make_float2(a.x + b.x, a.y + b.y);
        v[i + 1] = make_float2(a.x - b.x, a.y - b.y);
    }
#pragma unroll
    for (int i = 0; i < 8; i += 4) {
        cplx a = v[i], b = v[i + 2];
        v[i]     = make_float2(a.x + b.x, a.y + b.y);
        v[i + 2] = make_float2(a.x - b.x, a.y - b.y);
        cplx c1 = v[i + 1], d = v[i + 3];
        cplx dt = make_float2(-sgn * d.y, sgn * d.x);     // * (±i)
        v[i + 1] = make_float2(c1.x + dt.x, c1.y + dt.y);
        v[i + 3] = make_float2(c1.x - dt.x, c1.y - dt.y);
    }
    const float C = 0.70710678118654752440f;
    cplx a, b, bt;
    a = v[0]; b = v[4];
    v[0] = make_float2(a.x + b.x, a.y + b.y);
    v[4] = make_float2(a.x - b.x, a.y - b.y);
    a = v[1]; b = v[5]; bt = cmul(b, make_float2(C, sgn * C));
    v[1] = make_float2(a.x + bt.x, a.y + bt.y);
    v[5] = make_float2(a.x - bt.x, a.y - bt.y);
    a = v[2]; b = v[6]; bt = make_float2(-sgn * b.y, sgn * b.x);
    v[2] = make_float2(a.x + bt.x, a.y + bt.y);
    v[6] = make_float2(a.x - bt.x, a.y - bt.y);
    a = v[3]; b = v[7]; bt = cmul(b, make_float2(-C, sgn * C));
    v[3] = make_float2(a.x + bt.x, a.y + bt.y);
    v[7] = make_float2(a.x - bt.x, a.y - bt.y);
}

// Build w^1..w^7 from one sincos via shallow (depth<=3) cmul chains.
__device__ __forceinline__ void twiddle_powers(float ang, cplx w[8]) {
    float s, c;
    __sincosf(ang, &s, &c);
    w[1] = make_float2(c, s);
    w[2] = cmul(w[1], w[1]);
    w[3] = cmul(w[2], w[1]);
    w[4] = cmul(w[2], w[2]);
    w[5] = cmul(w[4], w[1]);
    w[6] = cmul(w[3], w[3]);
    w[7] = cmul(w[4], w[3]);
}

// One Stockham radix-8 pass over N=4096 in LDS, in place. 512 threads, j = tid.
// Reads at PAD(j)+544r; writes at PAD(base)+{r | 8r+(r>>1) | 68r | 544r}.
template <int NS>
__device__ __forceinline__ void fft_pass_ip(cplx* __restrict__ buf, int j, float sgn) {
    cplx* rp = buf + (j + (j >> 4));
    cplx v[8];
#pragma unroll
    for (int r = 0; r < 8; r++) v[r] = rp[544 * r];
    if (NS > 1) {
        int jm = j & (NS - 1);
        float ang = sgn * (TWO_PI / (float)(NS * 8)) * (float)jm;
        cplx w[8];
        twiddle_powers(ang, w);
#pragma unroll
        for (int r = 1; r < 8; r++) v[r] = cmul(v[r], w[r]);
    }
    dft8(v, sgn);
    __syncthreads();                       // everyone done reading
    int base = ((j & ~(NS - 1)) << 3) + (j & (NS - 1));
    cplx* wp = buf + (base + (base >> 4));
#pragma unroll
    for (int r = 0; r < 8; r++) {
        const int off = (NS == 1) ? r
                      : (NS == 8) ? (8 * r + (r >> 1))
                      : (NS == 64) ? (68 * r)
                      : (544 * r);
        wp[off] = v[r];
    }
    __syncthreads();
}

// Forward FFT pass 1 (NS=1) from registers (xv = lower half, upper half zero).
__device__ __forceinline__ void fft_pass1_fwd_regs(cplx* __restrict__ buf, int j,
                                                   const cplx xv[4]) {
    cplx v[8];
#pragma unroll
    for (int r = 0; r < 4; r++) v[r] = xv[r];
#pragma unroll
    for (int r = 4; r < 8; r++) v[r] = make_float2(0.f, 0.f);
    dft8(v, -1.0f);
    int b8 = 8 * j;
    cplx* wp = buf + (b8 + (b8 >> 4));
#pragma unroll
    for (int r = 0; r < 8; r++) wp[r] = v[r];
    __syncthreads();
}

// ---------------- Kernel 1: positional MLP -> h3T (64 x 4096) ----------------
__global__ __launch_bounds__(256) void mlp_kernel(
    const float* __restrict__ zin, const float* __restrict__ W1,
    const float* __restrict__ b1, const float* __restrict__ freq,
    const float* __restrict__ W2, const float* __restrict__ b2,
    const float* __restrict__ W3, const float* __restrict__ b3,
    float* __restrict__ h3T) {
    __shared__ float hs1[64][64];
    __shared__ float hs2[64][64];
    int tid = threadIdx.x;
    int l = tid & 63, w = tid >> 6;
    int lg = blockIdx.x * 64 + l;          // grid = 64 blocks covers 4096

    float zf[5];
#pragma unroll
    for (int e = 0; e < 5; e++) zf[e] = zin[lg * 5 + e];

    // layer 1
#pragma unroll
    for (int i = 0; i < 16; i++) {
        int o = w * 16 + i;
        float a = b1[o];
#pragma unroll
        for (int e = 0; e < 5; e++) a += W1[o * 5 + e] * zf[e];
        hs1[o][l] = __sinf(freq[o] * a);
    }
    __syncthreads();

    // layer 2
    float acc[16];
#pragma unroll
    for (int i = 0; i < 16; i++) acc[i] = b2[w * 16 + i];
#pragma unroll 8
    for (int o = 0; o < 64; o++) {
        float hv = hs1[o][l];
#pragma unroll
        for (int i = 0; i < 16; i++) acc[i] += W2[(w * 16 + i) * 64 + o] * hv;
    }
#pragma unroll
    for (int i = 0; i < 16; i++)
        hs2[w * 16 + i][l] = __sinf(freq[w * 16 + i] * acc[i]);
    __syncthreads();

    // layer 3
#pragma unroll
    for (int i = 0; i < 16; i++) acc[i] = b3[w * 16 + i];
#pragma unroll 8
    for (int o = 0; o < 64; o++) {
        float hv = hs2[o][l];
#pragma unroll
        for (int i = 0; i < 16; i++) acc[i] += W3[(w * 16 + i) * 64 + o] * hv;
    }
#pragma unroll
    for (int i = 0; i < 16; i++)
        h3T[(size_t)(w * 16 + i) * 4096 + lg] = __sinf(freq[w * 16 + i] * acc[i]);
}

// -------- Kernel 2: k[d,l] = <h3[:,l], W4[d,:]> * exp(-t[l]*|delta[d]|) --------
__global__ __launch_bounds__(256) void kgemm_kernel(
    const float* __restrict__ h3T, const float* __restrict__ W4,
    const float* __restrict__ tvec, const float* __restrict__ deltas,
    float* __restrict__ kout) {
    int lt = blockIdx.x & 3;       // l tile (4 x 1024)
    int dt = blockIdx.x >> 2;      // d tile (64 x 16)
    int l0 = lt * 1024 + threadIdx.x * 4;
    float4 acc[16];
#pragma unroll
    for (int i = 0; i < 16; i++) acc[i] = make_float4(0.f, 0.f, 0.f, 0.f);
#pragma unroll 8
    for (int o = 0; o < 64; o++) {
        float4 h = *(const float4*)(h3T + (size_t)o * 4096 + l0);
#pragma unroll
        for (int i = 0; i < 16; i++) {
            float wv = W4[(size_t)(dt * 16 + i) * 64 + o];
            acc[i].x += wv * h.x; acc[i].y += wv * h.y;
            acc[i].z += wv * h.z; acc[i].w += wv * h.w;
        }
    }
    float4 tl = *(const float4*)(tvec + l0);
#pragma unroll
    for (int i = 0; i < 16; i++) {
        int d = dt * 16 + i;
        float da = fabsf(deltas[d]);
        float4 o;
        o.x = acc[i].x * __expf(-tl.x * da);
        o.y = acc[i].y * __expf(-tl.y * da);
        o.z = acc[i].z * __expf(-tl.z * da);
        o.w = acc[i].w * __expf(-tl.w * da);
        *(float4*)(kout + (size_t)d * 4096 + l0) = o;
    }
}

// ------- Kernel 3: per-channel rfft(k,8192) -> Kf[d][0..4096] -------
// Kf stored with 1/4096 inverse-FFT scale folded in. Row stride 4104 complexes.
__global__ __launch_bounds__(512) void filter_fft_kernel(
    const float* __restrict__ kin, float2* __restrict__ Kf) {
    __shared__ cplx buf[4352];
    int d = blockIdx.x, t = threadIdx.x;

    // fwd pass 1 directly from global (pairs at m = t + r*512, r<4; rest zero)
    const cplx* k2 = (const cplx*)(kin + (size_t)d * 4096);
    cplx xv[4];
#pragma unroll
    for (int r = 0; r < 4; r++) xv[r] = k2[t + (r << 9)];
    fft_pass1_fwd_regs(buf, t, xv);
    fft_pass_ip<8>(buf, t, -1.0f);
    fft_pass_ip<64>(buf, t, -1.0f);
    fft_pass_ip<512>(buf, t, -1.0f);

    const float scale = 1.0f / 4096.0f;
    // W8192^(t + 512 i) = W8192^t * W16^i ; W16^i are compile-time constants.
    float sb, cb;
    __sincosf(-TWO_PI * (float)t * (1.0f / 8192.0f), &sb, &cb);
    cplx wk[4];
    wk[0] = make_float2(cb, sb);
    wk[1] = cmul(wk[0], make_float2(0.92387953251128675613f, -0.38268343236508977173f));
    wk[2] = cmul(wk[0], make_float2(0.70710678118654752440f, -0.70710678118654752440f));
    wk[3] = cmul(wk[0], make_float2(0.38268343236508977173f, -0.92387953251128675613f));

    // base pointers: rb -> Z[t+512i] ; qb2[544(3-i)] -> Z[4096-t-512i]
    cplx* rb  = buf + (t + (t >> 4));
    cplx* qb2 = buf + (((4096 - t) + ((4096 - t) >> 4)) - 1632);
    float2* KfRow = Kf + (size_t)d * 4104;
    float2* kfp = KfRow + t;               // + 512 i
    float2* kfq = KfRow + (4096 - t);      // - 512 i
#pragma unroll
    for (int i = 0; i < 4; i++) {
        if (t == 0 && i == 0) {            // bins 0, 4096, 2048 (thread 0 only)
            cplx z0 = buf[0];              // PAD(0)=0
            KfRow[0]    = make_float2((z0.x + z0.y) * scale, 0.f);
            KfRow[4096] = make_float2((z0.x - z0.y) * scale, 0.f);
            cplx zm = buf[PAD(2048)];
            KfRow[2048] = make_float2(zm.x * scale, -zm.y * scale);
        } else {
            cplx Zk = rb[544 * i];
            cplx Zq = qb2[544 * (3 - i)];
            cplx Fe = make_float2(0.5f * (Zk.x + Zq.x), 0.5f * (Zk.y - Zq.y));
            cplx Fo = make_float2(0.5f * (Zk.y + Zq.y), -0.5f * (Zk.x - Zq.x));
            cplx WFo = cmul(wk[i], Fo);
            kfp[512 * i]  = make_float2((Fe.x + WFo.x) * scale, (Fe.y + WFo.y) * scale);
            kfq[-512 * i] = make_float2((Fe.x - WFo.x) * scale, -(Fe.y - WFo.y) * scale);
        }
    }
}

// ------- Kernel 4: per (b,d) row: FFT -> spectral multiply -> IFFT -> +x*bias -------
__global__ __launch_bounds__(512) void conv_kernel(
    const float* __restrict__ x, const float2* __restrict__ Kf,
    const float* __restrict__ bias, float* __restrict__ out) {
    __shared__ cplx buf[4352];
    int rid = blockIdx.x;          // rid = b*1024 + d
    int d = rid & 1023;
    int t = threadIdx.x;

    // fwd pass 1 directly from global; keep x pairs in regs for the epilogue
    const cplx* x2 = (const cplx*)(x + (size_t)rid * 4096);
    cplx xv[4];
#pragma unroll
    for (int r = 0; r < 4; r++) xv[r] = x2[t + (r << 9)];
    fft_pass1_fwd_regs(buf, t, xv);
    fft_pass_ip<8>(buf, t, -1.0f);
    fft_pass_ip<64>(buf, t, -1.0f);
    fft_pass_ip<512>(buf, t, -1.0f);

    // spectral combine: each (k, 4096-k) pair owned by one thread -> in-place
    float sb, cb;
    __sincosf(-TWO_PI * (float)t * (1.0f / 8192.0f), &sb, &cb);
    cplx wk[4];
    wk[0] = make_float2(cb, sb);
    wk[1] = cmul(wk[0], make_float2(0.92387953251128675613f, -0.38268343236508977173f));
    wk[2] = cmul(wk[0], make_float2(0.70710678118654752440f, -0.70710678118654752440f));
    wk[3] = cmul(wk[0], make_float2(0.38268343236508977173f, -0.92387953251128675613f));

    cplx* rb  = buf + (t + (t >> 4));
    cplx* qb2 = buf + (((4096 - t) + ((4096 - t) >> 4)) - 1632);
    const float2* KfRow = Kf + (size_t)d * 4104;
    const float2* kfp = KfRow + t;
    const float2* kfq = KfRow + (4096 - t);
#pragma unroll
    for (int i = 0; i < 4; i++) {
        if (t == 0 && i == 0) {
            cplx z0 = buf[0];
            float U0 = z0.x + z0.y;
            float UN = z0.x - z0.y;
            float Y0 = U0 * KfRow[0].x;
            float YN = UN * KfRow[4096].x;
            buf[0] = make_float2(0.5f * (Y0 + YN), 0.5f * (Y0 - YN));
            cplx zm = buf[PAD(2048)];
            cplx Um = make_float2(zm.x, -zm.y);          // U[2048] = conj(Z[2048])
            cplx Ym = cmul(Um, KfRow[2048]);
            buf[PAD(2048)] = make_float2(Ym.x, -Ym.y);   // Z'[2048] = conj(Y)
        } else {
            cplx Zk = rb[544 * i];
            cplx Zq = qb2[544 * (3 - i)];
            cplx K1 = kfp[512 * i], K2 = kfq[-512 * i];
            cplx Fe = make_float2(0.5f * (Zk.x + Zq.x), 0.5f * (Zk.y - Zq.y));
            cplx Fo = make_float2(0.5f * (Zk.y + Zq.y), -0.5f * (Zk.x - Zq.x));
            cplx WFo = cmul(wk[i], Fo);
            cplx U1 = make_float2(Fe.x + WFo.x, Fe.y + WFo.y);
            cplx U2 = make_float2(Fe.x - WFo.x, -(Fe.y - WFo.y));  // conj(Fe - W*Fo)
            cplx Y1 = cmul(U1, K1);
            cplx Y2 = cmul(U2, K2);
            cplx FeY = make_float2(0.5f * (Y1.x + Y2.x), 0.5f * (Y1.y - Y2.y));
            cplx T   = make_float2(0.5f * (Y1.x - Y2.x), 0.5f * (Y1.y + Y2.y));
            cplx FoY = cmul(make_float2(wk[i].x, -wk[i].y), T);   // e^{+2πik/n} * T
            rb[544 * i]        = make_float2(FeY.x - FoY.y, FeY.y + FoY.x);
            qb2[544 * (3 - i)] = make_float2(FeY.x + FoY.y, FoY.x - FeY.y);
        }
    }
    __syncthreads();

    // inverse FFT; last pass fused with the global store (only m<2048 needed)
    fft_pass_ip<1>(buf, t, 1.0f);
    fft_pass_ip<8>(buf, t, 1.0f);
    fft_pass_ip<64>(buf, t, 1.0f);
    {
        cplx v[8];
#pragma unroll
        for (int r = 0; r < 8; r++) v[r] = rb[544 * r];
        float ang = (TWO_PI / 4096.0f) * (float)t;       // sgn=+1, NS=512
        cplx w[8];
        twiddle_powers(ang, w);
#pragma unroll
        for (int r = 1; r < 8; r++) v[r] = cmul(v[r], w[r]);
        dft8(v, 1.0f);
        float bd = bias[d];
        cplx* o2 = (cplx*)(out + (size_t)rid * 4096);
#pragma unroll
        for (int r = 0; r < 4; r++) {                    // m = t + r*512 < 2048
            cplx o;
            o.x = v[r].x + xv[r].x * bd;
            o.y = v[r].y + xv[r].y * bd;
            o2[t + (r << 9)] = o;
        }
    }
}

extern "C" void kernel_launch(void* const* d_in, const int* in_sizes, int n_in,
                              void* d_out, int out_size, void* d_ws, size_t ws_size,
                              hipStream_t stream) {
    const float* x      = (const float*)d_in[0];
    // d_in[1] = L (int scalar) — compile-time constant 4096 here
    const float* zin    = (const float*)d_in[2];
    const float* tvec   = (const float*)d_in[3];
    const float* deltas = (const float*)d_in[4];
    const float* W1     = (const float*)d_in[5];
    const float* b1     = (const float*)d_in[6];
    const float* freq   = (const float*)d_in[7];
    const float* W2     = (const float*)d_in[8];
    const float* b2     = (const float*)d_in[9];
    const float* W3     = (const float*)d_in[10];
    const float* b3     = (const float*)d_in[11];
    const float* W4     = (const float*)d_in[12];
    const float* bias   = (const float*)d_in[13];
    float* out = (float*)d_out;

    // ws layout: h3T (64 x 4096 f32 = 1 MB) | Kf (1024 rows * 4104 cplx = 33.6 MB)
    float*  h3T = (float*)d_ws;
    float2* Kf  = (float2*)((char*)d_ws + (size_t)64 * 4096 * sizeof(float));
    // k (1024x4096 f32 = 16 MB) staged in the tail of d_out (64 MB); conv
    // overwrites it afterwards (stream-ordered: kgemm -> filter_fft -> conv).
    float* kbuf = out + (size_t)3072 * 4096;

    mlp_kernel<<<64, 256, 0, stream>>>(zin, W1, b1, freq, W2, b2, W3, b3, h3T);
    kgemm_kernel<<<256, 256, 0, stream>>>(h3T, W4, tvec, deltas, kbuf);
    filter_fft_kernel<<<1024, 512, 0, stream>>>(kbuf, Kf);
    conv_kernel<<<4096, 512, 0, stream>>>(x, Kf, bias, out);
}

// Round 5
// 225.917 us; speedup vs baseline: 1.2030x; 1.0174x over previous
//
#include <hip/hip_runtime.h>
#include <math.h>

// Hyena filter: k = MLP(z)·decay ; out = irfft(rfft(x,8192)*rfft(k,8192))[:4096] + x*bias
// FFT: rfft(8192 real) via complex FFT of N=4096 (even/odd packing),
// radix-8 Stockham (4 passes), in-place in LDS.
// R6: strength-reduced LDS addressing (PAD identities), 1-sincos twiddle chains.
// R8: packed-FP32 via COMPILER-generated v_pk_* (R7's hand-written VOP3P asm
//     mis-encoded op_sel/neg and failed correctness). All complex math is
//     ext_vector(2) float arithmetic + __builtin_shufflevector/fneg swizzles:
//     LLVM selects v_pk_add/mul/fma_f32 on gfx950 and folds fneg into source
//     modifiers. Formulas are R6-exact (same constants, same t==0 branches);
//     only pass-1 zero-folding and the lower-half-only inverse epilogue DFT
//     are structural (algebra verified). Worst case = scalarized = R6 speed.

#define PAD(i) ((i) + ((i) >> 4))
#define TWO_PI 6.2831853071795864769f
#define C8 0.70710678118654752440f

typedef __attribute__((ext_vector_type(2))) float cplx;

static __device__ __forceinline__ cplx mkc(float x, float y) { cplx c; c.x = x; c.y = y; return c; }
static __device__ __forceinline__ cplx cswap(cplx v)  { return __builtin_shufflevector(v, v, 1, 0); }   // (y, x)
static __device__ __forceinline__ cplx cimul(cplx v)  { return __builtin_shufflevector(v, -v, 3, 0); }  // i*v  = (-y, x)
static __device__ __forceinline__ cplx cnimul(cplx v) { return __builtin_shufflevector(v, -v, 1, 2); }  // -i*v = (y, -x)
static __device__ __forceinline__ cplx cconj(cplx v)  { return __builtin_shufflevector(v, -v, 0, 3); }  // (x, -y)
static __device__ __forceinline__ cplx splx(cplx v)   { return __builtin_shufflevector(v, v, 0, 0); }
static __device__ __forceinline__ cplx sply(cplx v)   { return __builtin_shufflevector(v, v, 1, 1); }

// complex multiply a*b: pk_mul + pk_fma (+ swizzle)
static __device__ __forceinline__ cplx cmulv(cplx a, cplx b) {
    return splx(b) * a + sply(b) * cimul(a);
}
// conj(a)*b
static __device__ __forceinline__ cplx cmuljv(cplx a, cplx b) {
    return splx(a) * b + sply(a) * cnimul(b);
}

// 8-point DFT, natural order in/out. FWD: sgn=-1. (renamed dataflow of the
// verified scalar dft8: swap-free, stage outputs s*, g*)
template <bool FWD>
__device__ __forceinline__ void dft8_pk(cplx v[8]) {
    const cplx w15 = FWD ? mkc(C8, -C8) : mkc(C8, C8);
    const cplx w37 = FWD ? mkc(-C8, -C8) : mkc(-C8, C8);
    cplx s0 = v[0] + v[4], s1 = v[0] - v[4];
    cplx s2 = v[2] + v[6], s3 = v[2] - v[6];
    cplx s4 = v[1] + v[5], s5 = v[1] - v[5];
    cplx s6 = v[3] + v[7], s7 = v[3] - v[7];
    cplx g0 = s0 + s2, g2 = s0 - s2;
    cplx g1 = FWD ? (s1 + cnimul(s3)) : (s1 + cimul(s3));
    cplx g3 = FWD ? (s1 + cimul(s3)) : (s1 + cnimul(s3));
    cplx g4 = s4 + s6, g6 = s4 - s6;
    cplx g5 = FWD ? (s5 + cnimul(s7)) : (s5 + cimul(s7));
    cplx g7 = FWD ? (s5 + cimul(s7)) : (s5 + cnimul(s7));
    v[0] = g0 + g4; v[4] = g0 - g4;
    cplx bt1 = cmulv(g5, w15);
    v[1] = g1 + bt1; v[5] = g1 - bt1;
    v[2] = FWD ? (g2 + cnimul(g6)) : (g2 + cimul(g6));
    v[6] = FWD ? (g2 + cimul(g6)) : (g2 + cnimul(g6));
    cplx bt3 = cmulv(g7, w37);
    v[3] = g3 + bt3; v[7] = g3 - bt3;
}

// inverse dft8 computing only v[0..3] (epilogue needs lower half only)
__device__ __forceinline__ void dft8_lo4_inv(cplx v[8]) {
    const cplx w15 = mkc(C8, C8), w37 = mkc(-C8, C8);
    cplx s0 = v[0] + v[4], s1 = v[0] - v[4];
    cplx s2 = v[2] + v[6], s3 = v[2] - v[6];
    cplx s4 = v[1] + v[5], s5 = v[1] - v[5];
    cplx s6 = v[3] + v[7], s7 = v[3] - v[7];
    cplx g0 = s0 + s2, g2 = s0 - s2;
    cplx g1 = s1 + cimul(s3), g3 = s1 + cnimul(s3);
    cplx g4 = s4 + s6, g6 = s4 - s6;
    cplx g5 = s5 + cimul(s7), g7 = s5 + cnimul(s7);
    v[0] = g0 + g4;
    v[1] = g1 + cmulv(g5, w15);
    v[2] = g2 + cimul(g6);
    v[3] = g3 + cmulv(g7, w37);
}

// Build w^1..w^7 from one sincos via shallow (depth<=3) cmul chains.
__device__ __forceinline__ void twiddle_powers(float ang, cplx w[8]) {
    float s, c;
    __sincosf(ang, &s, &c);
    w[1] = mkc(c, s);
    w[2] = cmulv(w[1], w[1]);
    w[3] = cmulv(w[2], w[1]);
    w[4] = cmulv(w[2], w[2]);
    w[5] = cmulv(w[4], w[1]);
    w[6] = cmulv(w[3], w[3]);
    w[7] = cmulv(w[4], w[3]);
}

// One Stockham radix-8 pass over N=4096 in LDS, in place. 512 threads, j = tid.
// Reads at PAD(j)+544r; writes at PAD(base)+{r | 8r+(r>>1) | 68r | 544r}.
template <int NS, bool FWD>
__device__ __forceinline__ void fft_pass_ip(cplx* __restrict__ buf, int j) {
    cplx* rp = buf + (j + (j >> 4));
    cplx v[8];
#pragma unroll
    for (int r = 0; r < 8; r++) v[r] = rp[544 * r];
    if (NS > 1) {
        int jm = j & (NS - 1);
        float ang = (FWD ? -1.0f : 1.0f) * (TWO_PI / (float)(NS * 8)) * (float)jm;
        cplx w[8];
        twiddle_powers(ang, w);
#pragma unroll
        for (int r = 1; r < 8; r++) v[r] = cmulv(v[r], w[r]);
    }
    dft8_pk<FWD>(v);
    __syncthreads();                       // everyone done reading
    int base = ((j & ~(NS - 1)) << 3) + (j & (NS - 1));
    cplx* wp = buf + (base + (base >> 4));
#pragma unroll
    for (int r = 0; r < 8; r++) {
        const int off = (NS == 1) ? r
                      : (NS == 8) ? (8 * r + (r >> 1))
                      : (NS == 64) ? (68 * r)
                      : (544 * r);
        wp[off] = v[r];
    }
    __syncthreads();
}

// Forward FFT pass 1 (NS=1) from registers; upper half zero, hand-folded.
__device__ __forceinline__ void fft_pass1_fwd_regs(cplx* __restrict__ buf, int j,
                                                   const cplx xv[4]) {
    const cplx w15 = mkc(C8, -C8), w37 = mkc(-C8, -C8);
    cplx a0 = xv[0] + xv[2], a2 = xv[0] - xv[2];
    cplx a1 = xv[0] + cnimul(xv[2]), a3 = xv[0] + cimul(xv[2]);
    cplx b0 = xv[1] + xv[3], b2 = xv[1] - xv[3];
    cplx b1 = xv[1] + cnimul(xv[3]), b3 = xv[1] + cimul(xv[3]);
    cplx v[8];
    v[0] = a0 + b0; v[4] = a0 - b0;
    cplx bt1 = cmulv(b1, w15);
    v[1] = a1 + bt1; v[5] = a1 - bt1;
    v[2] = a2 + cnimul(b2); v[6] = a2 + cimul(b2);
    cplx bt3 = cmulv(b3, w37);
    v[3] = a3 + bt3; v[7] = a3 - bt3;
    int b8 = 8 * j;
    cplx* wp = buf + (b8 + (b8 >> 4));
#pragma unroll
    for (int r = 0; r < 8; r++) wp[r] = v[r];
    __syncthreads();
}

// ---------------- Kernel 1: positional MLP -> h3T (64 x 4096) ----------------
__global__ __launch_bounds__(256) void mlp_kernel(
    const float* __restrict__ zin, const float* __restrict__ W1,
    const float* __restrict__ b1, const float* __restrict__ freq,
    const float* __restrict__ W2, const float* __restrict__ b2,
    const float* __restrict__ W3, const float* __restrict__ b3,
    float* __restrict__ h3T) {
    __shared__ float hs1[64][64];
    __shared__ float hs2[64][64];
    int tid = threadIdx.x;
    int l = tid & 63, w = tid >> 6;
    int lg = blockIdx.x * 64 + l;          // grid = 64 blocks covers 4096

    float zf[5];
#pragma unroll
    for (int e = 0; e < 5; e++) zf[e] = zin[lg * 5 + e];

    // layer 1
#pragma unroll
    for (int i = 0; i < 16; i++) {
        int o = w * 16 + i;
        float a = b1[o];
#pragma unroll
        for (int e = 0; e < 5; e++) a += W1[o * 5 + e] * zf[e];
        hs1[o][l] = __sinf(freq[o] * a);
    }
    __syncthreads();

    // layer 2
    float acc[16];
#pragma unroll
    for (int i = 0; i < 16; i++) acc[i] = b2[w * 16 + i];
#pragma unroll 8
    for (int o = 0; o < 64; o++) {
        float hv = hs1[o][l];
#pragma unroll
        for (int i = 0; i < 16; i++) acc[i] += W2[(w * 16 + i) * 64 + o] * hv;
    }
#pragma unroll
    for (int i = 0; i < 16; i++)
        hs2[w * 16 + i][l] = __sinf(freq[w * 16 + i] * acc[i]);
    __syncthreads();

    // layer 3
#pragma unroll
    for (int i = 0; i < 16; i++) acc[i] = b3[w * 16 + i];
#pragma unroll 8
    for (int o = 0; o < 64; o++) {
        float hv = hs2[o][l];
#pragma unroll
        for (int i = 0; i < 16; i++) acc[i] += W3[(w * 16 + i) * 64 + o] * hv;
    }
#pragma unroll
    for (int i = 0; i < 16; i++)
        h3T[(size_t)(w * 16 + i) * 4096 + lg] = __sinf(freq[w * 16 + i] * acc[i]);
}

// -------- Kernel 2: k[d,l] = <h3[:,l], W4[d,:]> * exp(-t[l]*|delta[d]|) --------
__global__ __launch_bounds__(256) void kgemm_kernel(
    const float* __restrict__ h3T, const float* __restrict__ W4,
    const float* __restrict__ tvec, const float* __restrict__ deltas,
    float* __restrict__ kout) {
    int lt = blockIdx.x & 3;       // l tile (4 x 1024)
    int dt = blockIdx.x >> 2;      // d tile (64 x 16)
    int l0 = lt * 1024 + threadIdx.x * 4;
    float4 acc[16];
#pragma unroll
    for (int i = 0; i < 16; i++) acc[i] = make_float4(0.f, 0.f, 0.f, 0.f);
#pragma unroll 8
    for (int o = 0; o < 64; o++) {
        float4 h = *(const float4*)(h3T + (size_t)o * 4096 + l0);
#pragma unroll
        for (int i = 0; i < 16; i++) {
            float wv = W4[(size_t)(dt * 16 + i) * 64 + o];
            acc[i].x += wv * h.x; acc[i].y += wv * h.y;
            acc[i].z += wv * h.z; acc[i].w += wv * h.w;
        }
    }
    float4 tl = *(const float4*)(tvec + l0);
#pragma unroll
    for (int i = 0; i < 16; i++) {
        int d = dt * 16 + i;
        float da = fabsf(deltas[d]);
        float4 o;
        o.x = acc[i].x * __expf(-tl.x * da);
        o.y = acc[i].y * __expf(-tl.y * da);
        o.z = acc[i].z * __expf(-tl.z * da);
        o.w = acc[i].w * __expf(-tl.w * da);
        *(float4*)(kout + (size_t)d * 4096 + l0) = o;
    }
}

// ------- Kernel 3: per-channel rfft(k,8192) -> Kf[d][0..4096] -------
// Kf stored with 1/4096 inverse-FFT scale folded in. Row stride 4104 complexes.
__global__ __launch_bounds__(512) void filter_fft_kernel(
    const float* __restrict__ kin, cplx* __restrict__ Kf) {
    __shared__ cplx buf[4352];
    int d = blockIdx.x, t = threadIdx.x;

    const cplx* k2 = (const cplx*)(kin + (size_t)d * 4096);
    cplx xv[4];
#pragma unroll
    for (int r = 0; r < 4; r++) xv[r] = k2[t + (r << 9)];
    fft_pass1_fwd_regs(buf, t, xv);
    fft_pass_ip<8, true>(buf, t);
    fft_pass_ip<64, true>(buf, t);
    fft_pass_ip<512, true>(buf, t);

    const float scale = 1.0f / 4096.0f;
    // W8192^(t + 512 i) = W8192^t * W16^i ; W16^i compile-time.
    float sb, cb;
    __sincosf(-TWO_PI * (float)t * (1.0f / 8192.0f), &sb, &cb);
    cplx wk[4];
    wk[0] = mkc(cb, sb);
    wk[1] = cmulv(wk[0], mkc(0.92387953251128675613f, -0.38268343236508977173f));
    wk[2] = cmulv(wk[0], mkc(0.70710678118654752440f, -0.70710678118654752440f));
    wk[3] = cmulv(wk[0], mkc(0.38268343236508977173f, -0.92387953251128675613f));

    cplx* rb  = buf + (t + (t >> 4));
    cplx* qb2 = buf + (((4096 - t) + ((4096 - t) >> 4)) - 1632);
    cplx* KfRow = Kf + (size_t)d * 4104;
    cplx* kfp = KfRow + t;                 // + 512 i
    cplx* kfq = KfRow + (4096 - t);        // - 512 i
#pragma unroll
    for (int i = 0; i < 4; i++) {
        if (t == 0 && i == 0) {            // bins 0, 4096, 2048 (thread 0 only)
            cplx z0 = buf[0];              // PAD(0)=0
            KfRow[0]    = mkc((z0.x + z0.y) * scale, 0.f);
            KfRow[4096] = mkc((z0.x - z0.y) * scale, 0.f);
            cplx zm = buf[PAD(2048)];
            KfRow[2048] = mkc(zm.x * scale, -zm.y * scale);
        } else {
            cplx Zk = rb[544 * i];
            cplx Zq = qb2[544 * (3 - i)];
            cplx Fe = 0.5f * (Zk + cconj(Zq));            // (Zk.x+Zq.x, Zk.y-Zq.y)/2
            cplx Fo = 0.5f * (cnimul(Zk) + cswap(Zq));    // (Zk.y+Zq.y, Zq.x-Zk.x)/2
            cplx WFo = cmulv(wk[i], Fo);
            kfp[512 * i]  = scale * (Fe + WFo);
            kfq[-512 * i] = scale * cconj(Fe - WFo);
        }
    }
}

// ------- Kernel 4: per (b,d) row: FFT -> spectral multiply -> IFFT -> +x*bias -------
__global__ __launch_bounds__(512) void conv_kernel(
    const float* __restrict__ x, const cplx* __restrict__ Kf,
    const float* __restrict__ bias, float* __restrict__ out) {
    __shared__ cplx buf[4352];
    int rid = blockIdx.x;          // rid = b*1024 + d
    int d = rid & 1023;
    int t = threadIdx.x;

    const cplx* x2 = (const cplx*)(x + (size_t)rid * 4096);
    cplx xv[4];
#pragma unroll
    for (int r = 0; r < 4; r++) xv[r] = x2[t + (r << 9)];
    fft_pass1_fwd_regs(buf, t, xv);
    fft_pass_ip<8, true>(buf, t);
    fft_pass_ip<64, true>(buf, t);
    fft_pass_ip<512, true>(buf, t);

    // spectral combine: each (k, 4096-k) pair owned by one thread -> in-place
    float sb, cb;
    __sincosf(-TWO_PI * (float)t * (1.0f / 8192.0f), &sb, &cb);
    cplx wk[4];
    wk[0] = mkc(cb, sb);
    wk[1] = cmulv(wk[0], mkc(0.92387953251128675613f, -0.38268343236508977173f));
    wk[2] = cmulv(wk[0], mkc(0.70710678118654752440f, -0.70710678118654752440f));
    wk[3] = cmulv(wk[0], mkc(0.38268343236508977173f, -0.92387953251128675613f));

    cplx* rb  = buf + (t + (t >> 4));
    cplx* qb2 = buf + (((4096 - t) + ((4096 - t) >> 4)) - 1632);
    const cplx* KfRow = Kf + (size_t)d * 4104;
    const cplx* kfp = KfRow + t;
    const cplx* kfq = KfRow + (4096 - t);
#pragma unroll
    for (int i = 0; i < 4; i++) {
        if (t == 0 && i == 0) {
            cplx z0 = buf[0];
            float U0 = z0.x + z0.y;
            float UN = z0.x - z0.y;
            float Y0 = U0 * KfRow[0].x;
            float YN = UN * KfRow[4096].x;
            buf[0] = mkc(0.5f * (Y0 + YN), 0.5f * (Y0 - YN));
            cplx zm = buf[PAD(2048)];
            cplx Km = KfRow[2048];
            // Y = conj(Z[2048]) * K ; store conj(Y)
            cplx Ym = mkc(zm.x * Km.x + zm.y * Km.y, zm.x * Km.y - zm.y * Km.x);
            buf[PAD(2048)] = mkc(Ym.x, -Ym.y);
        } else {
            cplx Zk = rb[544 * i];
            cplx Zq = qb2[544 * (3 - i)];
            cplx K1 = kfp[512 * i], K2 = kfq[-512 * i];
            cplx Fe = 0.5f * (Zk + cconj(Zq));
            cplx Fo = 0.5f * (cnimul(Zk) + cswap(Zq));
            cplx WFo = cmulv(wk[i], Fo);
            cplx U1 = Fe + WFo;
            cplx U2 = cconj(Fe - WFo);
            cplx Y1 = cmulv(U1, K1);
            cplx Y2 = cmulv(U2, K2);
            cplx FeY = 0.5f * (Y1 + cconj(Y2));
            cplx T   = 0.5f * (Y1 - cconj(Y2));
            cplx FoY = cmuljv(wk[i], T);                 // conj(wk) * T
            rb[544 * i]        = FeY + cimul(FoY);
            qb2[544 * (3 - i)] = cconj(FeY - cimul(FoY));
        }
    }
    __syncthreads();

    // inverse FFT; last pass fused with the global store (only m<2048 needed)
    fft_pass_ip<1, false>(buf, t);
    fft_pass_ip<8, false>(buf, t);
    fft_pass_ip<64, false>(buf, t);
    {
        cplx v[8];
#pragma unroll
        for (int r = 0; r < 8; r++) v[r] = rb[544 * r];
        float ang = (TWO_PI / 4096.0f) * (float)t;       // inverse, NS=512
        cplx w[8];
        twiddle_powers(ang, w);
#pragma unroll
        for (int r = 1; r < 8; r++) v[r] = cmulv(v[r], w[r]);
        dft8_lo4_inv(v);
        float bd = bias[d];
        cplx* o2 = (cplx*)(out + (size_t)rid * 4096);
#pragma unroll
        for (int r = 0; r < 4; r++) {                    // m = t + r*512 < 2048
            o2[t + (r << 9)] = v[r] + bd * xv[r];
        }
    }
}

extern "C" void kernel_launch(void* const* d_in, const int* in_sizes, int n_in,
                              void* d_out, int out_size, void* d_ws, size_t ws_size,
                              hipStream_t stream) {
    const float* x      = (const float*)d_in[0];
    // d_in[1] = L (int scalar) — compile-time constant 4096 here
    const float* zin    = (const float*)d_in[2];
    const float* tvec   = (const float*)d_in[3];
    const float* deltas = (const float*)d_in[4];
    const float* W1     = (const float*)d_in[5];
    const float* b1     = (const float*)d_in[6];
    const float* freq   = (const float*)d_in[7];
    const float* W2     = (const float*)d_in[8];
    const float* b2     = (const float*)d_in[9];
    const float* W3     = (const float*)d_in[10];
    const float* b3     = (const float*)d_in[11];
    const float* W4     = (const float*)d_in[12];
    const float* bias   = (const float*)d_in[13];
    float* out = (float*)d_out;

    // ws layout: h3T (64 x 4096 f32 = 1 MB) | Kf (1024 rows * 4104 cplx = 33.6 MB)
    float* h3T = (float*)d_ws;
    cplx*  Kf  = (cplx*)((char*)d_ws + (size_t)64 * 4096 * sizeof(float));
    // k (1024x4096 f32 = 16 MB) staged in the tail of d_out (64 MB); conv
    // overwrites it afterwards (stream-ordered: kgemm -> filter_fft -> conv).
    float* kbuf = out + (size_t)3072 * 4096;

    mlp_kernel<<<64, 256, 0, stream>>>(zin, W1, b1, freq, W2, b2, W3, b3, h3T);
    kgemm_kernel<<<256, 256, 0, stream>>>(h3T, W4, tvec, deltas, kbuf);
    filter_fft_kernel<<<1024, 512, 0, stream>>>(kbuf, Kf);
    conv_kernel<<<4096, 512, 0, stream>>>(x, Kf, bias, out);
}